// Round 7
// baseline (866.111 us; speedup 1.0000x reference)
//
#include <hip/hip_runtime.h>
#include <hip/hip_bf16.h>
#include <cstddef>
#include <cstdint>

static constexpr int Cdim = 1024;
static constexpr int Bdim = 8;
static constexpr int NT   = 1024;
static constexpr int NM   = 2048;
static constexpr int Dh   = 128;
static constexpr int FF   = 4096;

typedef __attribute__((ext_vector_type(8))) short bf16x8_t;
typedef __attribute__((ext_vector_type(4))) float f32x4_t;

__device__ __forceinline__ float bf2f(unsigned int u16) {
    return __uint_as_float(u16 << 16);
}
__device__ __forceinline__ unsigned short f2bf(float f) {
    unsigned int u = __float_as_uint(f);
    u += 0x7fffu + ((u >> 16) & 1u);   // round-to-nearest-even (finite inputs)
    return (unsigned short)(u >> 16);
}

__device__ __forceinline__ void gload16(const void* g, void* l) {
    __builtin_amdgcn_global_load_lds(
        (const __attribute__((address_space(1))) void*)g,
        (__attribute__((address_space(3))) void*)l, 16, 0, 0);
}

// ---------------------------------------------------------------------------
// fp32 -> bf16 convert, 8 elements/thread, grid-stride.
// ---------------------------------------------------------------------------
__global__ __launch_bounds__(256)
void cvt_k(const float* __restrict__ in, unsigned short* __restrict__ out, int n8)
{
    const int stride = gridDim.x * 256;
    for (int i = blockIdx.x * 256 + threadIdx.x; i < n8; i += stride) {
        const float4 a = ((const float4*)in)[2*i];
        const float4 b = ((const float4*)in)[2*i+1];
        uint4 o;
        o.x = (unsigned)f2bf(a.x) | ((unsigned)f2bf(a.y) << 16);
        o.y = (unsigned)f2bf(a.z) | ((unsigned)f2bf(a.w) << 16);
        o.z = (unsigned)f2bf(b.x) | ((unsigned)f2bf(b.y) << 16);
        o.w = (unsigned)f2bf(b.z) | ((unsigned)f2bf(b.w) << 16);
        ((uint4*)out)[i] = o;
    }
}

// ---------------------------------------------------------------------------
// bf16 MFMA GEMM (m97 structure): out[r,c] = sum_k A[r,k]*W[c,k] + bias[c]
// A:[Rows,K] bf16 row-major, W:[Cout,K] bf16 row-major (both K-contiguous).
// 128x128 tile, BK=32, 256 threads = 4 waves in 2x2, each wave 4x4 frags of
// 16x16x32. Linear LDS + global_load_lds width 16. 2 barriers per K-step.
// XCD-aware bijective block swizzle (grid size always a multiple of 8).
// EPI: 0 bias, 1 bias+resid(fp32), 2 bias+relu. OBF: write bf16 else fp32.
// ---------------------------------------------------------------------------
template<int EPI, bool OBF>
__global__ __launch_bounds__(256)
void gemm_bf16_k(const unsigned short* __restrict__ A,
                 const unsigned short* __restrict__ W,
                 const float* __restrict__ bias, const float* __restrict__ resid,
                 void* __restrict__ outv, int Rows, int Cout, int K)
{
    __shared__ unsigned short As[128*32];   // row-major [128][32] (64B rows)
    __shared__ unsigned short Bs[128*32];
    const int gx  = gridDim.x;
    const int lin = blockIdx.y * gx + blockIdx.x;
    const int cpx = (gx * gridDim.y) >> 3;      // nwg % 8 == 0 by launch
    const int swz = (lin & 7) * cpx + (lin >> 3);
    const int bm = (swz / gx) * 128;
    const int bn = (swz % gx) * 128;
    const int t = threadIdx.x;
    const int w = t >> 6, l = t & 63;
    const int wr = w >> 1, wc = w & 1;

    f32x4_t acc[4][4];
    #pragma unroll
    for (int m = 0; m < 4; ++m)
        #pragma unroll
        for (int n = 0; n < 4; ++n) acc[m][n] = {0.f, 0.f, 0.f, 0.f};

    // staging: tile = 8 chunks of 1KB; wave w owns chunks 2w, 2w+1.
    // HW writes LDS at (uniform chunk base) + lane*16B; per-lane SOURCE
    // address must match: lane l -> row c*16 + l/4, k-chunk (l&3)*8.
    const int rA = 2*w*16 + (l >> 2);
    const int kc = (l & 3) * 8;
    const unsigned short* gA0 = A + (size_t)(bm + rA) * K + kc;
    const unsigned short* gA1 = gA0 + (size_t)16 * K;
    const unsigned short* gB0 = W + (size_t)(bn + rA) * K + kc;
    const unsigned short* gB1 = gB0 + (size_t)16 * K;
    unsigned short* lA0 = As + 2*w*512;         // wave-uniform LDS bases
    unsigned short* lA1 = As + (2*w+1)*512;
    unsigned short* lB0 = Bs + 2*w*512;
    unsigned short* lB1 = Bs + (2*w+1)*512;

    // fragment read bases (bytes): row*64 + kq*16
    const int frow = l & 15;
    const int kq   = l >> 4;
    const int abase = (wr*64 + frow)*64 + kq*16;
    const int bbase = (wc*64 + frow)*64 + kq*16;

    for (int k0 = 0; k0 < K; k0 += 32) {
        gload16(gA0, lA0); gload16(gA1, lA1);
        gload16(gB0, lB0); gload16(gB1, lB1);
        gA0 += 32; gA1 += 32; gB0 += 32; gB1 += 32;
        __syncthreads();                       // drains vmcnt+lgkmcnt
        bf16x8_t af[4], bfr[4];
        #pragma unroll
        for (int m = 0; m < 4; ++m)
            af[m] = *(const bf16x8_t*)((const char*)As + abase + m*1024);
        #pragma unroll
        for (int n = 0; n < 4; ++n)
            bfr[n] = *(const bf16x8_t*)((const char*)Bs + bbase + n*1024);
        #pragma unroll
        for (int m = 0; m < 4; ++m)
            #pragma unroll
            for (int n = 0; n < 4; ++n)
                acc[m][n] = __builtin_amdgcn_mfma_f32_16x16x32_bf16(
                                af[m], bfr[n], acc[m][n], 0, 0, 0);
        __syncthreads();                       // protect LDS before next stage
    }

    // C/D layout: col = lane&15, row = (lane>>4)*4 + reg   [m89/m91]
    const int col0 = l & 15;
    const int r0   = (l >> 4) * 4;
    float bv[4];
    #pragma unroll
    for (int n = 0; n < 4; ++n) bv[n] = bias[bn + wc*64 + n*16 + col0];

    #pragma unroll
    for (int m = 0; m < 4; ++m)
        #pragma unroll
        for (int r = 0; r < 4; ++r) {
            const int row = bm + wr*64 + m*16 + r0 + r;
            #pragma unroll
            for (int n = 0; n < 4; ++n) {
                const int col = bn + wc*64 + n*16 + col0;
                const size_t idx = (size_t)row * Cout + col;
                float v = acc[m][n][r] + bv[n];
                if (EPI == 1) v += resid[idx];
                if (EPI == 2) v = fmaxf(v, 0.f);
                if (OBF) ((unsigned short*)outv)[idx] = f2bf(v);
                else     ((float*)outv)[idx] = v;
            }
        }
}

// ---------------------------------------------------------------------------
// V transpose: kvff v-half [B,M,2C] (c = h*128+dd contiguous) ->
// vT[(b*8+h)*128+dd][m]  (m contiguous). 64x64 tiles through LDS.
// Write side XOR-swizzles 8-ushort column groups with (row>>3) so the scalar
// transpose writes (conflicting rows 8 apart at stride 80) spread across all
// 8 bank-quads; read applies the same XOR.
// ---------------------------------------------------------------------------
__global__ __launch_bounds__(256)
void vtrans_k(const unsigned short* __restrict__ kvb, unsigned short* __restrict__ vT)
{
    __shared__ unsigned short Ls[64][80];
    const int mt = blockIdx.x;               // 0..31
    const int ct = blockIdx.y;               // 0..15
    const int b  = blockIdx.z;               // 0..7
    const int t  = threadIdx.x;
    const int lr = t >> 3;                   // 0..31
    const int cc = (t & 7) * 8;
    #pragma unroll
    for (int i = 0; i < 2; ++i) {
        const int m = lr + i*32;
        const uint4 v = *(const uint4*)(kvb +
            ((size_t)(b*NM + mt*64 + m))*(2*Cdim) + Cdim + ct*64 + cc);
        const unsigned short* s = (const unsigned short*)&v;
        #pragma unroll
        for (int j = 0; j < 8; ++j) {
            const int row = cc + j;
            Ls[row][8*((m >> 3) ^ (row >> 3)) + (m & 7)] = s[j];
        }
    }
    __syncthreads();
    #pragma unroll
    for (int i = 0; i < 2; ++i) {
        const int c  = lr + i*32;
        const int cg = ct*64 + c;
        const int h  = cg >> 7, dd = cg & 127;
        const uint4 v = *(const uint4*)&Ls[c][8*((t & 7) ^ (c >> 3))];
        *(uint4*)(vT + ((size_t)((b*8 + h)*128 + dd))*NM + mt*64 + cc) = v;
    }
}

// ---------------------------------------------------------------------------
// MFMA flash cross-attention. 1 block = 64 queries x (b,h); 4 waves, each a
// 16-query strip. Q in registers; K staged to LDS via source-swizzled
// global_load_lds (wave-uniform LDS base; HW adds lane*16B); V from
// pre-transposed vT; P through swizzled LDS bf16 (per-wave strip, no extra
// barrier). Frag layouts as gemm_bf16_k. LDS 40KB -> 4 blocks/CU.
// ---------------------------------------------------------------------------
__global__ __launch_bounds__(256)
void flash_attn_k(const unsigned short* __restrict__ qh,
                  const unsigned short* __restrict__ kvb,
                  const unsigned short* __restrict__ vT,
                  unsigned short* __restrict__ ca)
{
    __shared__ unsigned short Ks [64*128];   // [key][d]  swizzled, 16KB
    __shared__ unsigned short VTs[128*64];   // [dd][k]   swizzled, 16KB
    __shared__ unsigned short Ps [64*64];    // [q][k]    swizzled,  8KB

    const int lin = blockIdx.y * 16 + blockIdx.x;    // nwg = 1024
    const int swz = (lin & 7) * 128 + (lin >> 3);    // T1 bijective
    const int qt = swz & 15;
    const int bh = swz >> 4;
    const int b = bh >> 3, h = bh & 7;
    const int t = threadIdx.x;
    const int w = t >> 6, l = t & 63;
    const float scale = 0.08838834764831845f;        // 1/sqrt(128)

    // ---- Q fragments (persistent): lane l holds q=w*16+(l&15), d-packed ----
    bf16x8_t aq[4];
    {
        const unsigned short* qbase = qh +
            ((size_t)(b*NT + qt*64 + w*16 + (l & 15)))*Cdim + h*Dh + (l >> 4)*8;
        #pragma unroll
        for (int kk = 0; kk < 4; ++kk)
            aq[kk] = *(const bf16x8_t*)(qbase + kk*32);
    }

    // ---- staging (wave w owns chunks 4w..4w+3 of each buffer) ----
    // K chunk = 4 key-rows x 256B: HW lane offset l*16B -> row l>>4, slot l&15.
    // V chunk = 8 dd-rows x 128B:  HW lane offset l*16B -> row l>>3, slot l&7.
    // Source col pre-swizzled (slot ^ row&7) so LDS stays linear (rule 21).
    const unsigned short* ksrc[4];
    const unsigned short* vsrc[4];
    #pragma unroll
    for (int j = 0; j < 4; ++j) {
        const int chunk = 4*w + j;
        const int krow  = chunk*4 + (l >> 4);
        ksrc[j] = kvb + (size_t)(b*NM + krow)*(2*Cdim) + h*Dh
                      + (((l & 15) ^ (krow & 7)) * 8);
        const int dd = chunk*8 + (l >> 3);
        vsrc[j] = vT + (size_t)(bh*128 + dd)*NM + (((l & 7) ^ (dd & 7)) * 8);
    }
    unsigned short* kdst = Ks  + 4*w*512;    // wave-uniform chunk bases
    unsigned short* vdst = VTs + 4*w*512;

    f32x4_t oacc[8];
    #pragma unroll
    for (int n = 0; n < 8; ++n) oacc[n] = {0.f, 0.f, 0.f, 0.f};
    float mrow[4] = {-1e30f, -1e30f, -1e30f, -1e30f};
    float lsum[4] = {0.f, 0.f, 0.f, 0.f};

    for (int m0 = 0; m0 < NM; m0 += 64) {
        __syncthreads();              // prev tile's readers done
        #pragma unroll
        for (int j = 0; j < 4; ++j) {
            gload16(ksrc[j] + (size_t)m0*(2*Cdim), kdst + j*512);
            gload16(vsrc[j] + m0,                  vdst + j*512);
        }
        __syncthreads();              // staged data visible (vmcnt drained)

        // ---- S = Q K^T : per wave 16q x 64k ----
        f32x4_t sacc[4];
        #pragma unroll
        for (int n = 0; n < 4; ++n) sacc[n] = {0.f, 0.f, 0.f, 0.f};
        #pragma unroll
        for (int n = 0; n < 4; ++n) {
            const int key = 16*n + (l & 15);
            #pragma unroll
            for (int kk = 0; kk < 4; ++kk) {
                const int slot = 4*kk + (l >> 4);
                const bf16x8_t bk = *(const bf16x8_t*)
                    (Ks + key*128 + ((slot ^ (key & 7)) * 8));
                sacc[n] = __builtin_amdgcn_mfma_f32_16x16x32_bf16(
                              aq[kk], bk, sacc[n], 0, 0, 0);
            }
        }

        // ---- online softmax; row q=(l>>4)*4+r lives in 16-lane groups ----
        #pragma unroll
        for (int r = 0; r < 4; ++r) {
            float s0 = sacc[0][r]*scale, s1 = sacc[1][r]*scale;
            float s2 = sacc[2][r]*scale, s3 = sacc[3][r]*scale;
            float cm = fmaxf(fmaxf(s0, s1), fmaxf(s2, s3));
            cm = fmaxf(cm, __shfl_xor(cm, 1, 16));
            cm = fmaxf(cm, __shfl_xor(cm, 2, 16));
            cm = fmaxf(cm, __shfl_xor(cm, 4, 16));
            cm = fmaxf(cm, __shfl_xor(cm, 8, 16));
            const float mnew = fmaxf(mrow[r], cm);
            const float corr = __expf(mrow[r] - mnew);
            mrow[r] = mnew;
            const float p0 = __expf(s0 - mnew), p1 = __expf(s1 - mnew);
            const float p2 = __expf(s2 - mnew), p3 = __expf(s3 - mnew);
            float rs = p0 + p1 + p2 + p3;
            rs += __shfl_xor(rs, 1, 16);
            rs += __shfl_xor(rs, 2, 16);
            rs += __shfl_xor(rs, 4, 16);
            rs += __shfl_xor(rs, 8, 16);
            lsum[r] = lsum[r]*corr + rs;
            #pragma unroll
            for (int n = 0; n < 8; ++n) oacc[n][r] *= corr;
            // write P row q (bf16, swizzled); each wave writes only its strip
            const int q = w*16 + (l >> 4)*4 + r;
            const float pv[4] = {p0, p1, p2, p3};
            #pragma unroll
            for (int n = 0; n < 4; ++n) {
                const int k = 16*n + (l & 15);
                Ps[q*64 + (((k >> 3) ^ (q & 7)) * 8) + (k & 7)] = f2bf(pv[n]);
            }
        }

        // ---- O += P V : per wave 16q x 128dd, contraction k=64 ----
        #pragma unroll
        for (int kk = 0; kk < 2; ++kk) {
            const int qa   = w*16 + (l & 15);
            const int slot = 4*kk + (l >> 4);
            const bf16x8_t pa = *(const bf16x8_t*)
                (Ps + qa*64 + ((slot ^ (qa & 7)) * 8));
            #pragma unroll
            for (int n = 0; n < 8; ++n) {
                const int dd = 16*n + (l & 15);
                const bf16x8_t bv = *(const bf16x8_t*)
                    (VTs + dd*64 + ((slot ^ (dd & 7)) * 8));
                oacc[n] = __builtin_amdgcn_mfma_f32_16x16x32_bf16(
                              pa, bv, oacc[n], 0, 0, 0);
            }
        }
    }

    // ---- epilogue: O[q][dd]/lsum -> bf16 ----
    #pragma unroll
    for (int r = 0; r < 4; ++r) {
        const float rinv = 1.0f / lsum[r];
        unsigned short* crow = ca +
            ((size_t)(b*NT + qt*64 + w*16 + (l >> 4)*4 + r))*Cdim + h*Dh + (l & 15);
        #pragma unroll
        for (int n = 0; n < 8; ++n)
            crow[16*n] = f2bf(oacc[n][r] * rinv);
    }
}

// ---------------------------------------------------------------------------
// LayerNorm over C=1024; one block per row; optional extra bf16 output.
// ---------------------------------------------------------------------------
template<bool DUAL>
__global__ __launch_bounds__(256)
void ln_k(const float* __restrict__ in, const float* __restrict__ gam,
          const float* __restrict__ bet, float* __restrict__ out,
          unsigned short* __restrict__ out_bf)
{
    __shared__ float red[8];
    const int row = blockIdx.x;
    const int t = threadIdx.x;
    const float4 x = *(const float4*)(in + (size_t)row*Cdim + t*4);
    float s = x.x + x.y + x.z + x.w;
    #pragma unroll
    for (int m = 1; m < 64; m <<= 1) s += __shfl_xor(s, m, 64);
    if ((t & 63) == 0) red[t >> 6] = s;
    __syncthreads();
    const float mean = (red[0]+red[1]+red[2]+red[3]) * (1.0f/1024.0f);
    const float dx = x.x-mean, dy = x.y-mean, dz = x.z-mean, dw = x.w-mean;
    float q = dx*dx + dy*dy + dz*dz + dw*dw;
    #pragma unroll
    for (int m = 1; m < 64; m <<= 1) q += __shfl_xor(q, m, 64);
    if ((t & 63) == 0) red[4 + (t >> 6)] = q;
    __syncthreads();
    const float var = (red[4]+red[5]+red[6]+red[7]) * (1.0f/1024.0f);
    const float inv = 1.0f / sqrtf(var + 1e-5f);
    const float4 g  = *(const float4*)(gam + t*4);
    const float4 bb = *(const float4*)(bet + t*4);
    const float r0 = dx*inv*g.x+bb.x, r1 = dy*inv*g.y+bb.y;
    const float r2 = dz*inv*g.z+bb.z, r3 = dw*inv*g.w+bb.w;
    *(float4*)(out + (size_t)row*Cdim + t*4) = make_float4(r0,r1,r2,r3);
    if (DUAL) {
        uint2 pk;
        pk.x = (unsigned)f2bf(r0) | ((unsigned)f2bf(r1) << 16);
        pk.y = (unsigned)f2bf(r2) | ((unsigned)f2bf(r3) << 16);
        *(uint2*)(out_bf + (size_t)row*Cdim + t*4) = pk;
    }
}

// ---------------------------------------------------------------------------
extern "C" void kernel_launch(void* const* d_in, const int* in_sizes, int n_in,
                              void* d_out, int out_size, void* d_ws, size_t ws_size,
                              hipStream_t stream)
{
    const float* tgt      = (const float*)d_in[0];
    const float* memory   = (const float*)d_in[1];
    const float* qkv_w    = (const float*)d_in[2];
    const float* qkv_b    = (const float*)d_in[3];
    const float* sa_out_w = (const float*)d_in[4];
    const float* sa_out_b = (const float*)d_in[5];
    const float* in_w     = (const float*)d_in[6];
    const float* in_b     = (const float*)d_in[7];
    const float* mha_w    = (const float*)d_in[8];
    const float* mha_b    = (const float*)d_in[9];
    const float* lin1_w   = (const float*)d_in[10];
    const float* lin1_b   = (const float*)d_in[11];
    const float* lin2_w   = (const float*)d_in[12];
    const float* lin2_b   = (const float*)d_in[13];
    const float* ln1_g    = (const float*)d_in[14];
    const float* ln1_bb   = (const float*)d_in[15];
    const float* ln2_g    = (const float*)d_in[16];
    const float* ln2_bb   = (const float*)d_in[17];
    const float* ln3_g    = (const float*)d_in[18];
    const float* ln3_bb   = (const float*)d_in[19];

    // ---- workspace layout, 220 MB total (liveness-aliased) ----
    const size_t MB = 1024*1024;
    if (ws_size < 220*MB) return;   // deterministic guard: no OOB page-fault;
                                    // harness then reports a clean mismatch.
    char* p = (char*)d_ws;
    unsigned short* wv   = (unsigned short*)p; p += 2*MB;   // qkv_w v-rows bf16
    unsigned short* wsa  = (unsigned short*)p; p += 2*MB;
    unsigned short* win  = (unsigned short*)p; p += 6*MB;   // all of in_proj_w
    unsigned short* wmh  = (unsigned short*)p; p += 2*MB;
    unsigned short* wl1  = (unsigned short*)p; p += 8*MB;
    unsigned short* wl2  = (unsigned short*)p; p += 8*MB;
    float* resb = (float*)p; p += 32*MB;                    // pre-LN residual; vT alias
    float* x12  = (float*)p; p += 32*MB;                    // x1, later x2
    unsigned short* kvff = (unsigned short*)p; p += 64*MB;  // kv bf16, later ff1
    unsigned short* vq   = (unsigned short*)p; p += 16*MB;  // vbf, later qhbf
    unsigned short* regG = (unsigned short*)p; p += 16*MB;  // tgtb, later x1b
    unsigned short* regH = (unsigned short*)p; p += 32*MB;  // memb, later cabf+x2b
    // vT [B*H*128, M] bf16 = 32MB lives ONLY between vtrans and flash_attn —
    // exactly resb's dead window (ln1 read -> mha-out write). Alias it.
    unsigned short* vT   = (unsigned short*)resb;
    unsigned short* tgtb = regG;
    unsigned short* x1b  = regG;
    unsigned short* memb = regH;
    unsigned short* cabf = regH;
    unsigned short* x2b  = (unsigned short*)((char*)regH + 16*MB);
    float* x1 = x12;
    float* x2 = x12;

    const int R  = Bdim * NT;    // 8192
    const int RM = Bdim * NM;    // 16384
    dim3 blk(256);
    auto cvgrid = [](int n8){ int b = (n8 + 255) / 256; return dim3(b > 2048 ? 2048 : b); };

    // fp32 -> bf16 converts
    cvt_k<<<cvgrid(R*Cdim/8),      blk, 0, stream>>>(tgt,                 tgtb, R*Cdim/8);
    cvt_k<<<cvgrid(RM*Cdim/8),     blk, 0, stream>>>(memory,              memb, RM*Cdim/8);
    cvt_k<<<cvgrid(Cdim*Cdim/8),   blk, 0, stream>>>(qkv_w + 2*Cdim*Cdim, wv,   Cdim*Cdim/8);
    cvt_k<<<cvgrid(Cdim*Cdim/8),   blk, 0, stream>>>(sa_out_w,            wsa,  Cdim*Cdim/8);
    cvt_k<<<cvgrid(3*Cdim*Cdim/8), blk, 0, stream>>>(in_w,                win,  3*Cdim*Cdim/8);
    cvt_k<<<cvgrid(Cdim*Cdim/8),   blk, 0, stream>>>(mha_w,               wmh,  Cdim*Cdim/8);
    cvt_k<<<cvgrid(FF*Cdim/8),     blk, 0, stream>>>(lin1_w,              wl1,  FF*Cdim/8);
    cvt_k<<<cvgrid(FF*Cdim/8),     blk, 0, stream>>>(lin2_w,              wl2,  FF*Cdim/8);

    // Self-attn degenerates to identity (diagonal mask): sa = (tgt@Wv^T+bv)@Wo^T+bo
    gemm_bf16_k<0,true ><<<dim3( 8,  64), blk, 0, stream>>>(tgtb, wv,  qkv_b + 2*Cdim, nullptr, vq,   R,  Cdim,   Cdim);
    gemm_bf16_k<1,false><<<dim3( 8,  64), blk, 0, stream>>>(vq,   wsa, sa_out_b,       tgt,     resb, R,  Cdim,   Cdim);
    ln_k<true ><<<dim3(R), blk, 0, stream>>>(resb, ln1_g, ln1_bb, x1, x1b);
    // q projection (bf16 out); vq dead -> reuse as qh
    gemm_bf16_k<0,true ><<<dim3( 8,  64), blk, 0, stream>>>(x1b,  win, in_b,           nullptr, vq,   R,  Cdim,   Cdim);
    // fused k+v projection of memory (rows C..3C of in_proj_w contiguous)
    gemm_bf16_k<0,true ><<<dim3(16, 128), blk, 0, stream>>>(memb, win + Cdim*Cdim, in_b + Cdim, nullptr, kvff, RM, 2*Cdim, Cdim);
    // V^T for MFMA PV (m-contiguous fragments); writes into resb's dead window
    vtrans_k<<<dim3(32, 16, 8), blk, 0, stream>>>(kvff, vT);
    flash_attn_k<<<dim3(16, 64), blk, 0, stream>>>(vq, kvff, vT, cabf);
    gemm_bf16_k<1,false><<<dim3( 8,  64), blk, 0, stream>>>(cabf, wmh, mha_b,          x1,      resb, R,  Cdim,   Cdim);
    ln_k<true ><<<dim3(R), blk, 0, stream>>>(resb, ln2_g, ln2_bb, x2, x2b);
    // FFN (kv dead after flash -> reuse kvff for ff1)
    gemm_bf16_k<2,true ><<<dim3(32,  64), blk, 0, stream>>>(x2b,  wl1, lin1_b,         nullptr, kvff, R,  FF,     Cdim);
    gemm_bf16_k<1,false><<<dim3( 8,  64), blk, 0, stream>>>(kvff, wl2, lin2_b,         x2,      resb, R,  Cdim,   FF);
    ln_k<false><<<dim3(R), blk, 0, stream>>>(resb, ln3_g, ln3_bb, (float*)d_out, nullptr);
}

// Round 8
// 838.305 us; speedup vs baseline: 1.0332x; 1.0332x over previous
//
#include <hip/hip_runtime.h>
#include <hip/hip_bf16.h>
#include <cstddef>
#include <cstdint>

static constexpr int Cdim = 1024;
static constexpr int Bdim = 8;
static constexpr int NT   = 1024;
static constexpr int NM   = 2048;
static constexpr int Dh   = 128;
static constexpr int FF   = 4096;

typedef __attribute__((ext_vector_type(8))) short bf16x8_t;
typedef __attribute__((ext_vector_type(4))) float f32x4_t;

__device__ __forceinline__ float bf2f(unsigned int u16) {
    return __uint_as_float(u16 << 16);
}
__device__ __forceinline__ unsigned short f2bf(float f) {
    unsigned int u = __float_as_uint(f);
    u += 0x7fffu + ((u >> 16) & 1u);   // round-to-nearest-even (finite inputs)
    return (unsigned short)(u >> 16);
}

__device__ __forceinline__ void gload16(const void* g, void* l) {
    __builtin_amdgcn_global_load_lds(
        (const __attribute__((address_space(1))) void*)g,
        (__attribute__((address_space(3))) void*)l, 16, 0, 0);
}

// ---------------------------------------------------------------------------
// Fused fp32 -> bf16 convert for all 8 tensors in ONE launch.
// Segment sizes are exact multiples of 1M floats; 512 blocks per 1M-float
// unit (256 thr x 8 floats). Segment chosen per block via cumulative table.
// ---------------------------------------------------------------------------
struct CvtArgs {
    const float* src[8];
    unsigned short* dst[8];
};

__global__ __launch_bounds__(256)
void cvt_all_k(CvtArgs a)
{
    // units (1M floats): tgt 8, mem 16, wv 1, wsa 1, win 3, wmh 1, wl1 4, wl2 4
    constexpr int cum[8] = {0, 8, 24, 25, 26, 29, 30, 34};
    const int u = blockIdx.x >> 9;
    int seg = 0;
    #pragma unroll
    for (int s = 1; s < 8; ++s) seg = (u >= cum[s]) ? s : seg;
    const size_t i8 = (size_t)(blockIdx.x - (cum[seg] << 9)) * 256 + threadIdx.x;
    const float* sp = a.src[seg] + i8 * 8;
    const float4 x = ((const float4*)sp)[0];
    const float4 y = ((const float4*)sp)[1];
    uint4 o;
    o.x = (unsigned)f2bf(x.x) | ((unsigned)f2bf(x.y) << 16);
    o.y = (unsigned)f2bf(x.z) | ((unsigned)f2bf(x.w) << 16);
    o.z = (unsigned)f2bf(y.x) | ((unsigned)f2bf(y.y) << 16);
    o.w = (unsigned)f2bf(y.z) | ((unsigned)f2bf(y.w) << 16);
    *(uint4*)(a.dst[seg] + i8 * 8) = o;
}

// ---------------------------------------------------------------------------
// bf16 MFMA GEMM (m97 structure) — UNCHANGED (validated R7).
// ---------------------------------------------------------------------------
template<int EPI, bool OBF>
__global__ __launch_bounds__(256)
void gemm_bf16_k(const unsigned short* __restrict__ A,
                 const unsigned short* __restrict__ W,
                 const float* __restrict__ bias, const float* __restrict__ resid,
                 void* __restrict__ outv, int Rows, int Cout, int K)
{
    __shared__ unsigned short As[128*32];
    __shared__ unsigned short Bs[128*32];
    const int gx  = gridDim.x;
    const int lin = blockIdx.y * gx + blockIdx.x;
    const int cpx = (gx * gridDim.y) >> 3;
    const int swz = (lin & 7) * cpx + (lin >> 3);
    const int bm = (swz / gx) * 128;
    const int bn = (swz % gx) * 128;
    const int t = threadIdx.x;
    const int w = t >> 6, l = t & 63;
    const int wr = w >> 1, wc = w & 1;

    f32x4_t acc[4][4];
    #pragma unroll
    for (int m = 0; m < 4; ++m)
        #pragma unroll
        for (int n = 0; n < 4; ++n) acc[m][n] = {0.f, 0.f, 0.f, 0.f};

    const int rA = 2*w*16 + (l >> 2);
    const int kc = (l & 3) * 8;
    const unsigned short* gA0 = A + (size_t)(bm + rA) * K + kc;
    const unsigned short* gA1 = gA0 + (size_t)16 * K;
    const unsigned short* gB0 = W + (size_t)(bn + rA) * K + kc;
    const unsigned short* gB1 = gB0 + (size_t)16 * K;
    unsigned short* lA0 = As + 2*w*512;
    unsigned short* lA1 = As + (2*w+1)*512;
    unsigned short* lB0 = Bs + 2*w*512;
    unsigned short* lB1 = Bs + (2*w+1)*512;

    const int frow = l & 15;
    const int kq   = l >> 4;
    const int abase = (wr*64 + frow)*64 + kq*16;
    const int bbase = (wc*64 + frow)*64 + kq*16;

    for (int k0 = 0; k0 < K; k0 += 32) {
        gload16(gA0, lA0); gload16(gA1, lA1);
        gload16(gB0, lB0); gload16(gB1, lB1);
        gA0 += 32; gA1 += 32; gB0 += 32; gB1 += 32;
        __syncthreads();
        bf16x8_t af[4], bfr[4];
        #pragma unroll
        for (int m = 0; m < 4; ++m)
            af[m] = *(const bf16x8_t*)((const char*)As + abase + m*1024);
        #pragma unroll
        for (int n = 0; n < 4; ++n)
            bfr[n] = *(const bf16x8_t*)((const char*)Bs + bbase + n*1024);
        #pragma unroll
        for (int m = 0; m < 4; ++m)
            #pragma unroll
            for (int n = 0; n < 4; ++n)
                acc[m][n] = __builtin_amdgcn_mfma_f32_16x16x32_bf16(
                                af[m], bfr[n], acc[m][n], 0, 0, 0);
        __syncthreads();
    }

    const int col0 = l & 15;
    const int r0   = (l >> 4) * 4;
    float bv[4];
    #pragma unroll
    for (int n = 0; n < 4; ++n) bv[n] = bias[bn + wc*64 + n*16 + col0];

    #pragma unroll
    for (int m = 0; m < 4; ++m)
        #pragma unroll
        for (int r = 0; r < 4; ++r) {
            const int row = bm + wr*64 + m*16 + r0 + r;
            #pragma unroll
            for (int n = 0; n < 4; ++n) {
                const int col = bn + wc*64 + n*16 + col0;
                const size_t idx = (size_t)row * Cout + col;
                float v = acc[m][n][r] + bv[n];
                if (EPI == 1) v += resid[idx];
                if (EPI == 2) v = fmaxf(v, 0.f);
                if (OBF) ((unsigned short*)outv)[idx] = f2bf(v);
                else     ((float*)outv)[idx] = v;
            }
        }
}

// ---------------------------------------------------------------------------
// V transpose — UNCHANGED (validated R7).
// ---------------------------------------------------------------------------
__global__ __launch_bounds__(256)
void vtrans_k(const unsigned short* __restrict__ kvb, unsigned short* __restrict__ vT)
{
    __shared__ unsigned short Ls[64][80];
    const int mt = blockIdx.x;
    const int ct = blockIdx.y;
    const int b  = blockIdx.z;
    const int t  = threadIdx.x;
    const int lr = t >> 3;
    const int cc = (t & 7) * 8;
    #pragma unroll
    for (int i = 0; i < 2; ++i) {
        const int m = lr + i*32;
        const uint4 v = *(const uint4*)(kvb +
            ((size_t)(b*NM + mt*64 + m))*(2*Cdim) + Cdim + ct*64 + cc);
        const unsigned short* s = (const unsigned short*)&v;
        #pragma unroll
        for (int j = 0; j < 8; ++j) {
            const int row = cc + j;
            Ls[row][8*((m >> 3) ^ (row >> 3)) + (m & 7)] = s[j];
        }
    }
    __syncthreads();
    #pragma unroll
    for (int i = 0; i < 2; ++i) {
        const int c  = lr + i*32;
        const int cg = ct*64 + c;
        const int h  = cg >> 7, dd = cg & 127;
        const uint4 v = *(const uint4*)&Ls[c][8*((t & 7) ^ (c >> 3))];
        *(uint4*)(vT + ((size_t)((b*8 + h)*128 + dd))*NM + mt*64 + cc) = v;
    }
}

// ---------------------------------------------------------------------------
// MFMA flash cross-attention v2: DOUBLE-BUFFERED K/V staging with counted
// vmcnt (T3/T4): prefetch tile t+1 before computing tile t; raw s_barrier
// (no vmcnt(0) drain) keeps 8 loads in flight across barriers. T5 setprio
// around MFMA clusters. LDS 72KB -> 2 blocks/CU. Layouts as R7 (validated).
// ---------------------------------------------------------------------------
__global__ __launch_bounds__(256)
void flash_attn_k(const unsigned short* __restrict__ qh,
                  const unsigned short* __restrict__ kvb,
                  const unsigned short* __restrict__ vT,
                  unsigned short* __restrict__ ca)
{
    __shared__ unsigned short Ks [2][64*128];   // [key][d] swizzled, 2x16KB
    __shared__ unsigned short VTs[2][128*64];   // [dd][k]  swizzled, 2x16KB
    __shared__ unsigned short Ps [64*64];       // [q][k]   swizzled,  8KB

    const int lin = blockIdx.y * 16 + blockIdx.x;    // nwg = 1024
    const int swz = (lin & 7) * 128 + (lin >> 3);    // T1 bijective
    const int qt = swz & 15;
    const int bh = swz >> 4;
    const int b = bh >> 3, h = bh & 7;
    const int t = threadIdx.x;
    const int w = t >> 6, l = t & 63;
    const float scale = 0.08838834764831845f;        // 1/sqrt(128)

    // Q fragments (persistent): lane l holds q=w*16+(l&15), d-packed
    bf16x8_t aq[4];
    {
        const unsigned short* qbase = qh +
            ((size_t)(b*NT + qt*64 + w*16 + (l & 15)))*Cdim + h*Dh + (l >> 4)*8;
        #pragma unroll
        for (int kk = 0; kk < 4; ++kk)
            aq[kk] = *(const bf16x8_t*)(qbase + kk*32);
    }

    // staging sources (R7-validated): K chunk = 4 rows x 256B, V chunk = 8 x 128B;
    // source col pre-swizzled (slot ^ row&7); LDS dest wave-uniform + lane*16B.
    const unsigned short* ksrc[4];
    const unsigned short* vsrc[4];
    #pragma unroll
    for (int j = 0; j < 4; ++j) {
        const int chunk = 4*w + j;
        const int krow  = chunk*4 + (l >> 4);
        ksrc[j] = kvb + (size_t)(b*NM + krow)*(2*Cdim) + h*Dh
                      + (((l & 15) ^ (krow & 7)) * 8);
        const int dd = chunk*8 + (l >> 3);
        vsrc[j] = vT + (size_t)(bh*128 + dd)*NM + (((l & 7) ^ (dd & 7)) * 8);
    }

    f32x4_t oacc[8];
    #pragma unroll
    for (int n = 0; n < 8; ++n) oacc[n] = {0.f, 0.f, 0.f, 0.f};
    float mrow[4] = {-1e30f, -1e30f, -1e30f, -1e30f};
    float lsum[4] = {0.f, 0.f, 0.f, 0.f};

    // prologue: stage tile 0 -> buf 0 (8 gload_lds per lane)
    #pragma unroll
    for (int j = 0; j < 4; ++j) {
        gload16(ksrc[j], &Ks[0][4*w*512 + j*512]);
        gload16(vsrc[j], &VTs[0][4*w*512 + j*512]);
    }

    for (int tt = 0; tt < 32; ++tt) {
        const int buf = tt & 1;
        if (tt < 31) {
            // prefetch tile tt+1 into the other buffer (issued, not waited)
            const size_t koff = (size_t)((tt + 1) * 64) * (2*Cdim);
            const int    moff = (tt + 1) * 64;
            #pragma unroll
            for (int j = 0; j < 4; ++j) {
                gload16(ksrc[j] + koff, &Ks[buf ^ 1][4*w*512 + j*512]);
                gload16(vsrc[j] + moff, &VTs[buf ^ 1][4*w*512 + j*512]);
            }
            // wait for tile tt's 8 loads only; the 8 just issued stay in flight
            asm volatile("s_waitcnt vmcnt(8)" ::: "memory");
        } else {
            asm volatile("s_waitcnt vmcnt(0)" ::: "memory");
        }
        __builtin_amdgcn_sched_barrier(0);
        __builtin_amdgcn_s_barrier();          // tile tt visible to all waves

        // ---- S = Q K^T : per wave 16q x 64k ----
        f32x4_t sacc[4];
        #pragma unroll
        for (int n = 0; n < 4; ++n) sacc[n] = {0.f, 0.f, 0.f, 0.f};
        __builtin_amdgcn_s_setprio(1);
        #pragma unroll
        for (int n = 0; n < 4; ++n) {
            const int key = 16*n + (l & 15);
            #pragma unroll
            for (int kk = 0; kk < 4; ++kk) {
                const int slot = 4*kk + (l >> 4);
                const bf16x8_t bk = *(const bf16x8_t*)
                    (&Ks[buf][key*128 + ((slot ^ (key & 7)) * 8)]);
                sacc[n] = __builtin_amdgcn_mfma_f32_16x16x32_bf16(
                              aq[kk], bk, sacc[n], 0, 0, 0);
            }
        }
        __builtin_amdgcn_s_setprio(0);

        // ---- online softmax; row q=(l>>4)*4+r lives in 16-lane groups ----
        #pragma unroll
        for (int r = 0; r < 4; ++r) {
            float s0 = sacc[0][r]*scale, s1 = sacc[1][r]*scale;
            float s2 = sacc[2][r]*scale, s3 = sacc[3][r]*scale;
            float cm = fmaxf(fmaxf(s0, s1), fmaxf(s2, s3));
            cm = fmaxf(cm, __shfl_xor(cm, 1, 16));
            cm = fmaxf(cm, __shfl_xor(cm, 2, 16));
            cm = fmaxf(cm, __shfl_xor(cm, 4, 16));
            cm = fmaxf(cm, __shfl_xor(cm, 8, 16));
            const float mnew = fmaxf(mrow[r], cm);
            const float corr = __expf(mrow[r] - mnew);
            mrow[r] = mnew;
            const float p0 = __expf(s0 - mnew), p1 = __expf(s1 - mnew);
            const float p2 = __expf(s2 - mnew), p3 = __expf(s3 - mnew);
            float rs = p0 + p1 + p2 + p3;
            rs += __shfl_xor(rs, 1, 16);
            rs += __shfl_xor(rs, 2, 16);
            rs += __shfl_xor(rs, 4, 16);
            rs += __shfl_xor(rs, 8, 16);
            lsum[r] = lsum[r]*corr + rs;
            #pragma unroll
            for (int n = 0; n < 8; ++n) oacc[n][r] *= corr;
            // write P row q (bf16, swizzled); per-wave strip -> no barrier
            const int q = w*16 + (l >> 4)*4 + r;
            const float pv[4] = {p0, p1, p2, p3};
            #pragma unroll
            for (int n = 0; n < 4; ++n) {
                const int k = 16*n + (l & 15);
                Ps[q*64 + (((k >> 3) ^ (q & 7)) * 8) + (k & 7)] = f2bf(pv[n]);
            }
        }

        // ---- O += P V : per wave 16q x 128dd, contraction k=64 ----
        __builtin_amdgcn_s_setprio(1);
        #pragma unroll
        for (int kk = 0; kk < 2; ++kk) {
            const int qa   = w*16 + (l & 15);
            const int slot = 4*kk + (l >> 4);
            const bf16x8_t pa = *(const bf16x8_t*)
                (Ps + qa*64 + ((slot ^ (qa & 7)) * 8));
            #pragma unroll
            for (int n = 0; n < 8; ++n) {
                const int dd = 16*n + (l & 15);
                const bf16x8_t bv = *(const bf16x8_t*)
                    (&VTs[buf][dd*64 + ((slot ^ (dd & 7)) * 8)]);
                oacc[n] = __builtin_amdgcn_mfma_f32_16x16x32_bf16(
                              pa, bv, oacc[n], 0, 0, 0);
            }
        }
        __builtin_amdgcn_s_setprio(0);

        __builtin_amdgcn_sched_barrier(0);
        __builtin_amdgcn_s_barrier();   // all waves done reading buf -> safe to overwrite
    }

    // ---- epilogue: O[q][dd]/lsum -> bf16 ----
    #pragma unroll
    for (int r = 0; r < 4; ++r) {
        const float rinv = 1.0f / lsum[r];
        unsigned short* crow = ca +
            ((size_t)(b*NT + qt*64 + w*16 + (l >> 4)*4 + r))*Cdim + h*Dh + (l & 15);
        #pragma unroll
        for (int n = 0; n < 8; ++n)
            crow[16*n] = f2bf(oacc[n][r] * rinv);
    }
}

// ---------------------------------------------------------------------------
// LayerNorm v2: one WAVE per row (16 elems/lane), 4 rows per block.
// No LDS, no barriers; reductions via width-64 shuffles.
// ---------------------------------------------------------------------------
template<bool DUAL>
__global__ __launch_bounds__(256)
void ln_k(const float* __restrict__ in, const float* __restrict__ gam,
          const float* __restrict__ bet, float* __restrict__ out,
          unsigned short* __restrict__ out_bf)
{
    const int row = blockIdx.x*4 + (threadIdx.x >> 6);
    const int l   = threadIdx.x & 63;
    const float* rp = in + (size_t)row*Cdim;
    float4 x[4];
    #pragma unroll
    for (int j = 0; j < 4; ++j) x[j] = *(const float4*)(rp + j*256 + l*4);
    float s = 0.f;
    #pragma unroll
    for (int j = 0; j < 4; ++j) s += x[j].x + x[j].y + x[j].z + x[j].w;
    #pragma unroll
    for (int m = 1; m < 64; m <<= 1) s += __shfl_xor(s, m, 64);
    const float mean = s * (1.0f/1024.0f);
    float q = 0.f;
    #pragma unroll
    for (int j = 0; j < 4; ++j) {
        const float dx = x[j].x-mean, dy = x[j].y-mean;
        const float dz = x[j].z-mean, dw = x[j].w-mean;
        q += dx*dx + dy*dy + dz*dz + dw*dw;
    }
    #pragma unroll
    for (int m = 1; m < 64; m <<= 1) q += __shfl_xor(q, m, 64);
    const float inv = 1.0f / sqrtf(q * (1.0f/1024.0f) + 1e-5f);
    #pragma unroll
    for (int j = 0; j < 4; ++j) {
        const float4 g  = *(const float4*)(gam + j*256 + l*4);
        const float4 bb = *(const float4*)(bet + j*256 + l*4);
        const float r0 = (x[j].x-mean)*inv*g.x + bb.x;
        const float r1 = (x[j].y-mean)*inv*g.y + bb.y;
        const float r2 = (x[j].z-mean)*inv*g.z + bb.z;
        const float r3 = (x[j].w-mean)*inv*g.w + bb.w;
        *(float4*)(out + (size_t)row*Cdim + j*256 + l*4) = make_float4(r0,r1,r2,r3);
        if (DUAL) {
            uint2 pk;
            pk.x = (unsigned)f2bf(r0) | ((unsigned)f2bf(r1) << 16);
            pk.y = (unsigned)f2bf(r2) | ((unsigned)f2bf(r3) << 16);
            *(uint2*)(out_bf + (size_t)row*Cdim + j*256 + l*4) = pk;
        }
    }
}

// ---------------------------------------------------------------------------
extern "C" void kernel_launch(void* const* d_in, const int* in_sizes, int n_in,
                              void* d_out, int out_size, void* d_ws, size_t ws_size,
                              hipStream_t stream)
{
    const float* tgt      = (const float*)d_in[0];
    const float* memory   = (const float*)d_in[1];
    const float* qkv_w    = (const float*)d_in[2];
    const float* qkv_b    = (const float*)d_in[3];
    const float* sa_out_w = (const float*)d_in[4];
    const float* sa_out_b = (const float*)d_in[5];
    const float* in_w     = (const float*)d_in[6];
    const float* in_b     = (const float*)d_in[7];
    const float* mha_w    = (const float*)d_in[8];
    const float* mha_b    = (const float*)d_in[9];
    const float* lin1_w   = (const float*)d_in[10];
    const float* lin1_b   = (const float*)d_in[11];
    const float* lin2_w   = (const float*)d_in[12];
    const float* lin2_b   = (const float*)d_in[13];
    const float* ln1_g    = (const float*)d_in[14];
    const float* ln1_bb   = (const float*)d_in[15];
    const float* ln2_g    = (const float*)d_in[16];
    const float* ln2_bb   = (const float*)d_in[17];
    const float* ln3_g    = (const float*)d_in[18];
    const float* ln3_bb   = (const float*)d_in[19];

    // ---- workspace layout, 220 MB total (liveness-aliased; validated R7) ----
    const size_t MB = 1024*1024;
    if (ws_size < 220*MB) return;
    char* p = (char*)d_ws;
    unsigned short* wv   = (unsigned short*)p; p += 2*MB;
    unsigned short* wsa  = (unsigned short*)p; p += 2*MB;
    unsigned short* win  = (unsigned short*)p; p += 6*MB;
    unsigned short* wmh  = (unsigned short*)p; p += 2*MB;
    unsigned short* wl1  = (unsigned short*)p; p += 8*MB;
    unsigned short* wl2  = (unsigned short*)p; p += 8*MB;
    float* resb = (float*)p; p += 32*MB;                    // pre-LN residual; vT alias
    float* x12  = (float*)p; p += 32*MB;                    // x1, later x2
    unsigned short* kvff = (unsigned short*)p; p += 64*MB;  // kv bf16, later ff1
    unsigned short* vq   = (unsigned short*)p; p += 16*MB;  // vbf, later qhbf
    unsigned short* regG = (unsigned short*)p; p += 16*MB;  // tgtb, later x1b
    unsigned short* regH = (unsigned short*)p; p += 32*MB;  // memb, later cabf+x2b
    unsigned short* vT   = (unsigned short*)resb;           // resb dead window
    unsigned short* tgtb = regG;
    unsigned short* x1b  = regG;
    unsigned short* memb = regH;
    unsigned short* cabf = regH;
    unsigned short* x2b  = (unsigned short*)((char*)regH + 16*MB);
    float* x1 = x12;
    float* x2 = x12;

    const int R  = Bdim * NT;    // 8192
    const int RM = Bdim * NM;    // 16384
    dim3 blk(256);

    // fused fp32 -> bf16 converts (one launch; 38 x 1M-float units)
    CvtArgs cva;
    cva.src[0] = tgt;                  cva.dst[0] = tgtb;
    cva.src[1] = memory;               cva.dst[1] = memb;
    cva.src[2] = qkv_w + 2*Cdim*Cdim;  cva.dst[2] = wv;
    cva.src[3] = sa_out_w;             cva.dst[3] = wsa;
    cva.src[4] = in_w;                 cva.dst[4] = win;
    cva.src[5] = mha_w;                cva.dst[5] = wmh;
    cva.src[6] = lin1_w;               cva.dst[6] = wl1;
    cva.src[7] = lin2_w;               cva.dst[7] = wl2;
    cvt_all_k<<<dim3(38*512), blk, 0, stream>>>(cva);

    // Self-attn degenerates to identity (diagonal mask): sa = (tgt@Wv^T+bv)@Wo^T+bo
    gemm_bf16_k<0,true ><<<dim3( 8,  64), blk, 0, stream>>>(tgtb, wv,  qkv_b + 2*Cdim, nullptr, vq,   R,  Cdim,   Cdim);
    gemm_bf16_k<1,false><<<dim3( 8,  64), blk, 0, stream>>>(vq,   wsa, sa_out_b,       tgt,     resb, R,  Cdim,   Cdim);
    ln_k<true ><<<dim3(R/4), blk, 0, stream>>>(resb, ln1_g, ln1_bb, x1, x1b);
    // q projection (bf16 out); vq dead -> reuse as qh
    gemm_bf16_k<0,true ><<<dim3( 8,  64), blk, 0, stream>>>(x1b,  win, in_b,           nullptr, vq,   R,  Cdim,   Cdim);
    // fused k+v projection of memory (rows C..3C of in_proj_w contiguous)
    gemm_bf16_k<0,true ><<<dim3(16, 128), blk, 0, stream>>>(memb, win + Cdim*Cdim, in_b + Cdim, nullptr, kvff, RM, 2*Cdim, Cdim);
    // V^T for MFMA PV; lives in resb's dead window
    vtrans_k<<<dim3(32, 16, 8), blk, 0, stream>>>(kvff, vT);
    flash_attn_k<<<dim3(16, 64), blk, 0, stream>>>(vq, kvff, vT, cabf);
    gemm_bf16_k<1,false><<<dim3( 8,  64), blk, 0, stream>>>(cabf, wmh, mha_b,          x1,      resb, R,  Cdim,   Cdim);
    ln_k<true ><<<dim3(R/4), blk, 0, stream>>>(resb, ln2_g, ln2_bb, x2, x2b);
    // FFN (kv dead after flash -> reuse kvff for ff1)
    gemm_bf16_k<2,true ><<<dim3(32,  64), blk, 0, stream>>>(x2b,  wl1, lin1_b,         nullptr, kvff, R,  FF,     Cdim);
    gemm_bf16_k<1,false><<<dim3( 8,  64), blk, 0, stream>>>(kvff, wl2, lin2_b,         x2,      resb, R,  Cdim,   FF);
    ln_k<false><<<dim3(R/4), blk, 0, stream>>>(resb, ln3_g, ln3_bb, (float*)d_out, nullptr);
}